// Round 12
// baseline (3164.254 us; speedup 1.0000x reference)
//
#include <hip/hip_runtime.h>

#define NEG_SLOPE 0.2f
#define NBK 128          // nodes per bucket
#define BKT_SHIFT 7
#define NB 2500          // bucket count (N = 320000 = 2500*128)
#define CHUNK 4096       // edges per partition block
#define EPT 16           // edges per thread in partition (256*16 = 4096)
#define BATCH 8          // edges per group per iteration (branch-free)

__device__ __forceinline__ float lrelu(float x) { return x >= 0.f ? x : NEG_SLOPE * x; }

// ---------------------------------------------------------- bucket histogram
__global__ __launch_bounds__(256) void k_hist(const int* __restrict__ dst, int E,
                                              int* __restrict__ counts) {
    __shared__ int cnt[NB];
    int t = threadIdx.x;
    for (int b = t; b < NB; b += 256) cnt[b] = 0;
    __syncthreads();
    int base = blockIdx.x * CHUNK;
#pragma unroll
    for (int k = 0; k < EPT; k++) {
        int idx = base + k * 256 + t;
        if (idx < E) atomicAdd(&cnt[dst[idx] >> BKT_SHIFT], 1);
    }
    __syncthreads();
    for (int b = t; b < NB; b += 256) {
        int c = cnt[b];
        if (c) atomicAdd(&counts[b], c);
    }
}

// ---------------------------------------------------------- bucket scan (1 block)
__global__ __launch_bounds__(256) void k_scan(const int* __restrict__ counts,
                                              int* __restrict__ offs,
                                              int* __restrict__ cursorB, int E) {
    __shared__ int part[256];
    int t = threadIdx.x;
    const int PER = (NB + 255) / 256;  // 10
    int lo = t * PER, hi = min(lo + PER, NB);
    int s = 0;
    for (int i = lo; i < hi; i++) s += counts[i];
    part[t] = s;
    __syncthreads();
    for (int off = 1; off < 256; off <<= 1) {
        int v = (t >= off) ? part[t - off] : 0;
        __syncthreads();
        part[t] += v;
        __syncthreads();
    }
    int run = part[t] - s;  // exclusive base
    for (int i = lo; i < hi; i++) {
        offs[i] = run;
        cursorB[i] = run;
        run += counts[i];
    }
    if (t == 255) offs[NB] = E;
}

// ---------------------------------------------------------- bucket partition
// Packs (src, dst&127) into one int: src<2^19, dl<2^7 -> 26 bits.
__global__ __launch_bounds__(256) void k_partition(const int* __restrict__ src,
                                                   const int* __restrict__ dst, int E,
                                                   int* __restrict__ cursorB,
                                                   int* __restrict__ pairs) {
    __shared__ int cnt[NB];
    __shared__ int base[NB];
    __shared__ int cnt2[NB];
    int t = threadIdx.x;
    for (int b = t; b < NB; b += 256) { cnt[b] = 0; cnt2[b] = 0; }
    __syncthreads();

    int s[EPT], d[EPT];
    int cbase = blockIdx.x * CHUNK;
#pragma unroll
    for (int k = 0; k < EPT; k++) {
        int idx = cbase + k * 256 + t;
        if (idx < E) {
            s[k] = src[idx];
            d[k] = dst[idx];
            atomicAdd(&cnt[d[k] >> BKT_SHIFT], 1);
        } else {
            d[k] = -1;
        }
    }
    __syncthreads();
    for (int b = t; b < NB; b += 256) {
        int c = cnt[b];
        if (c) base[b] = atomicAdd(&cursorB[b], c);
    }
    __syncthreads();
#pragma unroll
    for (int k = 0; k < EPT; k++) {
        if (d[k] >= 0) {
            int b = d[k] >> BKT_SHIFT;
            int pos = base[b] + atomicAdd(&cnt2[b], 1);
            pairs[pos] = (s[k] << BKT_SHIFT) | (d[k] & (NBK - 1));
        }
    }
}

// ---------------------------------------------------------- dense transform
template <int K>
__global__ __launch_bounds__(256) void k_transform(
    const float* __restrict__ h, const float* __restrict__ W,
    const float* __restrict__ a_s, const float* __restrict__ a_d,
    float* __restrict__ hs, float* __restrict__ asrc, float* __restrict__ adst, int N) {
    __shared__ float Ws[K * 32];
    __shared__ float as_s[32], ad_s[32];
    int t = threadIdx.x;
    for (int i = t; i < K * 32; i += 256) Ws[i] = W[i];
    if (t < 32) { as_s[t] = a_s[t]; ad_s[t] = a_d[t]; }
    __syncthreads();

    int n = blockIdx.x * 8 + (t >> 5);
    int d = t & 31;
    if (n >= N) return;

    float hval = (d < K) ? h[n * K + d] : 0.f;
    float acc = 0.f;
#pragma unroll
    for (int k = 0; k < K; k++) {
        float hk = __shfl(hval, k, 32);
        acc += hk * Ws[k * 32 + d];
    }
    hs[n * 32 + d] = acc;

    float r1 = acc * as_s[d];
    float r2 = acc * ad_s[d];
#pragma unroll
    for (int off = 16; off > 0; off >>= 1) {
        r1 += __shfl_xor(r1, off, 32);
        r2 += __shfl_xor(r2, off, 32);
    }
    if (d == 0) { asrc[n] = r1; adst[n] = r2; }
}

// ---------------------------------------------------------- bucketed gather
// One block per 128-node bucket. Branch-free batch-8 main loop (forces 8
// independent hs-row loads in flight per 32-lane group); adst slice staged
// in LDS (one fewer global load per edge); scalar tail loop.
__global__ __launch_bounds__(256, 6) void k_gather(
    const float* __restrict__ hs, const float* __restrict__ asrc,
    const float* __restrict__ adst, const int* __restrict__ offs,
    const int* __restrict__ pairs, const float* __restrict__ bias,
    float* __restrict__ out) {
    __shared__ float acc[NBK * 32];
    __shared__ float den[NBK];
    __shared__ float adst_s[NBK];
    int t = threadIdx.x;
    int node0 = blockIdx.x << BKT_SHIFT;
    for (int i = t; i < NBK * 32; i += 256) acc[i] = 0.f;
    if (t < NBK) {
        den[t] = 0.f;
        adst_s[t] = adst[node0 + t];
    }
    __syncthreads();

    int d = t & 31;
    int g = t >> 5;  // 8 edge-groups
    int beg = offs[blockIdx.x], end = offs[blockIdx.x + 1];

    int e0 = beg + g * BATCH;
    // branch-free full batches: 8 independent pk loads -> 16 independent
    // (asrc, hs) loads -> compute. No per-element predication.
    for (; e0 + BATCH <= end; e0 += 8 * BATCH) {
        int pk[BATCH];
        float as[BATCH], v[BATCH];
#pragma unroll
        for (int k = 0; k < BATCH; k++) pk[k] = pairs[e0 + k];
#pragma unroll
        for (int k = 0; k < BATCH; k++) {
            int s = pk[k] >> BKT_SHIFT;
            as[k] = asrc[s];
            v[k] = hs[s * 32 + d];
        }
#pragma unroll
        for (int k = 0; k < BATCH; k++) {
            int dl = pk[k] & (NBK - 1);
            float ex = __expf(lrelu(as[k] + adst_s[dl]));
            atomicAdd(&acc[dl * 32 + d], ex * v[k]);
            if (d == 0) atomicAdd(&den[dl], ex);
        }
    }
    // tail (at most BATCH-1 edges for this group)
    int etail = min(e0 + BATCH, end);
    for (int e = e0; e < etail; e++) {
        int pk = pairs[e];
        int s = pk >> BKT_SHIFT;
        int dl = pk & (NBK - 1);
        float ex = __expf(lrelu(asrc[s] + adst_s[dl]));
        atomicAdd(&acc[dl * 32 + d], ex * hs[s * 32 + d]);
        if (d == 0) atomicAdd(&den[dl], ex);
    }
    __syncthreads();

    float bd = bias[d];
    for (int ln = g; ln < NBK; ln += 8) {
        int n = node0 + ln;
        float exs = __expf(lrelu(asrc[n] + adst_s[ln]));  // self loop
        float v = hs[n * 32 + d];
        float num = acc[ln * 32 + d] + exs * v;
        float dn = den[ln] + exs;
        out[n * 32 + d] = fmaxf(num / dn + bd, 0.f);
    }
}

// ---------------------------------------------------------------- launcher
extern "C" void kernel_launch(void* const* d_in, const int* in_sizes, int n_in,
                              void* d_out, int out_size, void* d_ws, size_t ws_size,
                              hipStream_t stream) {
    const float* x      = (const float*)d_in[0];
    const int*   ei     = (const int*)d_in[1];
    const float* W0     = (const float*)d_in[2];
    const float* a_src0 = (const float*)d_in[3];
    const float* a_dst0 = (const float*)d_in[4];
    const float* b0     = (const float*)d_in[5];
    const float* W      = (const float*)d_in[6];
    const float* a_src  = (const float*)d_in[7];
    const float* a_dst  = (const float*)d_in[8];
    const float* b      = (const float*)d_in[9];

    const int F = 3;
    const int N = in_sizes[0] / F;   // 320000
    const int E = in_sizes[1] / 2;   // 5120000
    const int* src = ei;
    const int* dst = ei + E;

    // workspace carve
    int*   pairs   = (int*)d_ws;                         // E (packed src|dl)
    float* HS      = (float*)(pairs + E);                // N*32
    float* asrcv   = HS + (size_t)N * 32;                // N
    float* adstv   = asrcv + N;                          // N
    int*   counts  = (int*)(adstv + N);                  // NB
    int*   offs    = counts + NB;                        // NB+1
    int*   cursorB = offs + NB + 1;                      // NB
    float* outp    = (float*)d_out;

    const int T = 256;
    int nchunks = (E + CHUNK - 1) / CHUNK;  // 1250

    // ---- bucket partition build (once; shared by all 3 layers) ----
    hipMemsetAsync(counts, 0, NB * sizeof(int), stream);
    k_hist<<<nchunks, T, 0, stream>>>(dst, E, counts);
    k_scan<<<1, T, 0, stream>>>(counts, offs, cursorB, E);
    k_partition<<<nchunks, T, 0, stream>>>(src, dst, E, cursorB, pairs);

    dim3 gridT(N / 8);   // 8 nodes / block
    dim3 gridG(NB);      // 1 bucket / block

    // ---- layer 0: x(N,3) -> d_out ----
    k_transform<3><<<gridT, T, 0, stream>>>(x, W0, a_src0, a_dst0, HS, asrcv, adstv, N);
    k_gather<<<gridG, T, 0, stream>>>(HS, asrcv, adstv, offs, pairs, b0, outp);

    // ---- layer 1: d_out -> d_out ----
    k_transform<32><<<gridT, T, 0, stream>>>(outp, W, a_src, a_dst, HS, asrcv, adstv, N);
    k_gather<<<gridG, T, 0, stream>>>(HS, asrcv, adstv, offs, pairs, b, outp);

    // ---- layer 2: d_out -> d_out ----
    k_transform<32><<<gridT, T, 0, stream>>>(outp, W + 1024, a_src + 32, a_dst + 32,
                                             HS, asrcv, adstv, N);
    k_gather<<<gridG, T, 0, stream>>>(HS, asrcv, adstv, offs, pairs, b + 32, outp);
}

// Round 14
// 3153.664 us; speedup vs baseline: 1.0034x; 1.0034x over previous
//
#include <hip/hip_runtime.h>

#define NEG_SLOPE 0.2f
#define NBK 128          // nodes per bucket
#define BKT_SHIFT 7
#define NB 2500          // bucket count (N = 320000 = 2500*128)
#define CHUNK 4096       // edges per partition block
#define EPT 16           // edges per thread in partition (256*16 = 4096)
#define ACCW 33          // padded acc row stride (bank = (dl+d)&31)

__device__ __forceinline__ float lrelu(float x) { return x >= 0.f ? x : NEG_SLOPE * x; }

// ---------------------------------------------------------- bucket histogram
__global__ __launch_bounds__(256) void k_hist(const int* __restrict__ dst, int E,
                                              int* __restrict__ counts) {
    __shared__ int cnt[NB];
    int t = threadIdx.x;
    for (int b = t; b < NB; b += 256) cnt[b] = 0;
    __syncthreads();
    int base = blockIdx.x * CHUNK;
#pragma unroll
    for (int k = 0; k < EPT; k++) {
        int idx = base + k * 256 + t;
        if (idx < E) atomicAdd(&cnt[dst[idx] >> BKT_SHIFT], 1);
    }
    __syncthreads();
    for (int b = t; b < NB; b += 256) {
        int c = cnt[b];
        if (c) atomicAdd(&counts[b], c);
    }
}

// ---------------------------------------------------------- bucket scan (1 block)
__global__ __launch_bounds__(256) void k_scan(const int* __restrict__ counts,
                                              int* __restrict__ offs,
                                              int* __restrict__ cursorB, int E) {
    __shared__ int part[256];
    int t = threadIdx.x;
    const int PER = (NB + 255) / 256;  // 10
    int lo = t * PER, hi = min(lo + PER, NB);
    int s = 0;
    for (int i = lo; i < hi; i++) s += counts[i];
    part[t] = s;
    __syncthreads();
    for (int off = 1; off < 256; off <<= 1) {
        int v = (t >= off) ? part[t - off] : 0;
        __syncthreads();
        part[t] += v;
        __syncthreads();
    }
    int run = part[t] - s;  // exclusive base
    for (int i = lo; i < hi; i++) {
        offs[i] = run;
        cursorB[i] = run;
        run += counts[i];
    }
    if (t == 255) offs[NB] = E;
}

// ---------------------------------------------------------- bucket partition
// Packs (src, dst&127) into one int: src<2^19, dl<2^7 -> 26 bits.
__global__ __launch_bounds__(256) void k_partition(const int* __restrict__ src,
                                                   const int* __restrict__ dst, int E,
                                                   int* __restrict__ cursorB,
                                                   int* __restrict__ pairs) {
    __shared__ int cnt[NB];
    __shared__ int base[NB];
    __shared__ int cnt2[NB];
    int t = threadIdx.x;
    for (int b = t; b < NB; b += 256) { cnt[b] = 0; cnt2[b] = 0; }
    __syncthreads();

    int s[EPT], d[EPT];
    int cbase = blockIdx.x * CHUNK;
#pragma unroll
    for (int k = 0; k < EPT; k++) {
        int idx = cbase + k * 256 + t;
        if (idx < E) {
            s[k] = src[idx];
            d[k] = dst[idx];
            atomicAdd(&cnt[d[k] >> BKT_SHIFT], 1);
        } else {
            d[k] = -1;
        }
    }
    __syncthreads();
    for (int b = t; b < NB; b += 256) {
        int c = cnt[b];
        if (c) base[b] = atomicAdd(&cursorB[b], c);
    }
    __syncthreads();
#pragma unroll
    for (int k = 0; k < EPT; k++) {
        if (d[k] >= 0) {
            int b = d[k] >> BKT_SHIFT;
            int pos = base[b] + atomicAdd(&cnt2[b], 1);
            pairs[pos] = (s[k] << BKT_SHIFT) | (d[k] & (NBK - 1));
        }
    }
}

// ---------------------------------------------------------- dense transform
template <int K>
__global__ __launch_bounds__(256) void k_transform(
    const float* __restrict__ h, const float* __restrict__ W,
    const float* __restrict__ a_s, const float* __restrict__ a_d,
    float* __restrict__ hs, float* __restrict__ asrc, float* __restrict__ adst, int N) {
    __shared__ float Ws[K * 32];
    __shared__ float as_s[32], ad_s[32];
    int t = threadIdx.x;
    for (int i = t; i < K * 32; i += 256) Ws[i] = W[i];
    if (t < 32) { as_s[t] = a_s[t]; ad_s[t] = a_d[t]; }
    __syncthreads();

    int n = blockIdx.x * 8 + (t >> 5);
    int d = t & 31;
    if (n >= N) return;

    float hval = (d < K) ? h[n * K + d] : 0.f;
    float acc = 0.f;
#pragma unroll
    for (int k = 0; k < K; k++) {
        float hk = __shfl(hval, k, 32);
        acc += hk * Ws[k * 32 + d];
    }
    hs[n * 32 + d] = acc;

    float r1 = acc * as_s[d];
    float r2 = acc * ad_s[d];
#pragma unroll
    for (int off = 16; off > 0; off >>= 1) {
        r1 += __shfl_xor(r1, off, 32);
        r2 += __shfl_xor(r2, off, 32);
    }
    if (d == 0) { asrc[n] = r1; adst[n] = r2; }
}

// ---------------------------------------------------------- bucketed gather
// One block per 128-node bucket. ONE EDGE PER LANE: each lane loads its
// edge's full 128-B hs row as 8 named float4s (8 independent dwordx4 ->
// ~640 lines in flight per wave), computes exp once, scatters 32 products
// into stride-33-padded LDS acc (bank = (dl+d)&31, spread by random dl).
__global__ __launch_bounds__(256, 6) void k_gather(
    const float* __restrict__ hs, const float* __restrict__ asrc,
    const float* __restrict__ adst, const int* __restrict__ offs,
    const int* __restrict__ pairs, const float* __restrict__ bias,
    float* __restrict__ out) {
    __shared__ float acc[NBK * ACCW];
    __shared__ float den[NBK];
    __shared__ float adst_s[NBK];
    int t = threadIdx.x;
    int node0 = blockIdx.x << BKT_SHIFT;
    for (int i = t; i < NBK * ACCW; i += 256) acc[i] = 0.f;
    if (t < NBK) {
        den[t] = 0.f;
        adst_s[t] = adst[node0 + t];
    }
    __syncthreads();

    int beg = offs[blockIdx.x], end = offs[blockIdx.x + 1];
    const float4* __restrict__ hs4 = (const float4*)hs;

#define ACC4(J, R)                                  \
    atomicAdd(ap + 4 * J + 0, ex * R.x);            \
    atomicAdd(ap + 4 * J + 1, ex * R.y);            \
    atomicAdd(ap + 4 * J + 2, ex * R.z);            \
    atomicAdd(ap + 4 * J + 3, ex * R.w)

    for (int e = beg + t; e < end; e += 256) {
        int pk = pairs[e];
        int s = pk >> BKT_SHIFT;
        int dl = pk & (NBK - 1);
        float asv = asrc[s];
        int rb = s << 3;
        float4 r0 = hs4[rb + 0];
        float4 r1 = hs4[rb + 1];
        float4 r2 = hs4[rb + 2];
        float4 r3 = hs4[rb + 3];
        float4 r4 = hs4[rb + 4];
        float4 r5 = hs4[rb + 5];
        float4 r6 = hs4[rb + 6];
        float4 r7 = hs4[rb + 7];
        float ex = __expf(lrelu(asv + adst_s[dl]));
        float* ap = &acc[dl * ACCW];
        atomicAdd(&den[dl], ex);
        ACC4(0, r0); ACC4(1, r1); ACC4(2, r2); ACC4(3, r3);
        ACC4(4, r4); ACC4(5, r5); ACC4(6, r6); ACC4(7, r7);
    }
#undef ACC4
    __syncthreads();

    int d = t & 31;
    int g = t >> 5;
    float bd = bias[d];
    for (int ln = g; ln < NBK; ln += 8) {
        int n = node0 + ln;
        float exs = __expf(lrelu(asrc[n] + adst_s[ln]));  // self loop
        float v = hs[n * 32 + d];
        float num = acc[ln * ACCW + d] + exs * v;
        float dn = den[ln] + exs;
        out[n * 32 + d] = fmaxf(num / dn + bd, 0.f);
    }
}

// ---------------------------------------------------------------- launcher
extern "C" void kernel_launch(void* const* d_in, const int* in_sizes, int n_in,
                              void* d_out, int out_size, void* d_ws, size_t ws_size,
                              hipStream_t stream) {
    const float* x      = (const float*)d_in[0];
    const int*   ei     = (const int*)d_in[1];
    const float* W0     = (const float*)d_in[2];
    const float* a_src0 = (const float*)d_in[3];
    const float* a_dst0 = (const float*)d_in[4];
    const float* b0     = (const float*)d_in[5];
    const float* W      = (const float*)d_in[6];
    const float* a_src  = (const float*)d_in[7];
    const float* a_dst  = (const float*)d_in[8];
    const float* b      = (const float*)d_in[9];

    const int F = 3;
    const int N = in_sizes[0] / F;   // 320000
    const int E = in_sizes[1] / 2;   // 5120000
    const int* src = ei;
    const int* dst = ei + E;

    // workspace carve
    int*   pairs   = (int*)d_ws;                         // E (packed src|dl)
    float* HS      = (float*)(pairs + E);                // N*32
    float* asrcv   = HS + (size_t)N * 32;                // N
    float* adstv   = asrcv + N;                          // N
    int*   counts  = (int*)(adstv + N);                  // NB
    int*   offs    = counts + NB;                        // NB+1
    int*   cursorB = offs + NB + 1;                      // NB
    float* outp    = (float*)d_out;

    const int T = 256;
    int nchunks = (E + CHUNK - 1) / CHUNK;  // 1250

    // ---- bucket partition build (once; shared by all 3 layers) ----
    hipMemsetAsync(counts, 0, NB * sizeof(int), stream);
    k_hist<<<nchunks, T, 0, stream>>>(dst, E, counts);
    k_scan<<<1, T, 0, stream>>>(counts, offs, cursorB, E);
    k_partition<<<nchunks, T, 0, stream>>>(src, dst, E, cursorB, pairs);

    dim3 gridT(N / 8);   // 8 nodes / block
    dim3 gridG(NB);      // 1 bucket / block

    // ---- layer 0: x(N,3) -> d_out ----
    k_transform<3><<<gridT, T, 0, stream>>>(x, W0, a_src0, a_dst0, HS, asrcv, adstv, N);
    k_gather<<<gridG, T, 0, stream>>>(HS, asrcv, adstv, offs, pairs, b0, outp);

    // ---- layer 1: d_out -> d_out ----
    k_transform<32><<<gridT, T, 0, stream>>>(outp, W, a_src, a_dst, HS, asrcv, adstv, N);
    k_gather<<<gridG, T, 0, stream>>>(HS, asrcv, adstv, offs, pairs, b, outp);

    // ---- layer 2: d_out -> d_out ----
    k_transform<32><<<gridT, T, 0, stream>>>(outp, W + 1024, a_src + 32, a_dst + 32,
                                             HS, asrcv, adstv, N);
    k_gather<<<gridG, T, 0, stream>>>(HS, asrcv, adstv, offs, pairs, b + 32, outp);
}

// Round 15
// 3149.538 us; speedup vs baseline: 1.0047x; 1.0013x over previous
//
#include <hip/hip_runtime.h>

#define NEG_SLOPE 0.2f
#define NBK 128          // nodes per bucket
#define BKT_SHIFT 7
#define NB 2500          // bucket count (N = 320000 = 2500*128)
#define CHUNK 4096       // edges per partition block
#define EPT 16           // edges per thread in partition (256*16 = 4096)
#define ACCW 33          // padded acc row stride (bank = (dl+d)&31)

__device__ __forceinline__ float lrelu(float x) { return x >= 0.f ? x : NEG_SLOPE * x; }

// ---------------------------------------------------------- bucket histogram
__global__ __launch_bounds__(256) void k_hist(const int* __restrict__ dst, int E,
                                              int* __restrict__ counts) {
    __shared__ int cnt[NB];
    int t = threadIdx.x;
    for (int b = t; b < NB; b += 256) cnt[b] = 0;
    __syncthreads();
    int base = blockIdx.x * CHUNK;
#pragma unroll
    for (int k = 0; k < EPT; k++) {
        int idx = base + k * 256 + t;
        if (idx < E) atomicAdd(&cnt[dst[idx] >> BKT_SHIFT], 1);
    }
    __syncthreads();
    for (int b = t; b < NB; b += 256) {
        int c = cnt[b];
        if (c) atomicAdd(&counts[b], c);
    }
}

// ---------------------------------------------------------- bucket scan (1 block)
__global__ __launch_bounds__(256) void k_scan(const int* __restrict__ counts,
                                              int* __restrict__ offs,
                                              int* __restrict__ cursorB, int E) {
    __shared__ int part[256];
    int t = threadIdx.x;
    const int PER = (NB + 255) / 256;  // 10
    int lo = t * PER, hi = min(lo + PER, NB);
    int s = 0;
    for (int i = lo; i < hi; i++) s += counts[i];
    part[t] = s;
    __syncthreads();
    for (int off = 1; off < 256; off <<= 1) {
        int v = (t >= off) ? part[t - off] : 0;
        __syncthreads();
        part[t] += v;
        __syncthreads();
    }
    int run = part[t] - s;  // exclusive base
    for (int i = lo; i < hi; i++) {
        offs[i] = run;
        cursorB[i] = run;
        run += counts[i];
    }
    if (t == 255) offs[NB] = E;
}

// ---------------------------------------------------------- bucket partition
// Packs (src, dst&127) into one int: src<2^19, dl<2^7 -> 26 bits.
__global__ __launch_bounds__(256) void k_partition(const int* __restrict__ src,
                                                   const int* __restrict__ dst, int E,
                                                   int* __restrict__ cursorB,
                                                   int* __restrict__ pairs) {
    __shared__ int cnt[NB];
    __shared__ int base[NB];
    __shared__ int cnt2[NB];
    int t = threadIdx.x;
    for (int b = t; b < NB; b += 256) { cnt[b] = 0; cnt2[b] = 0; }
    __syncthreads();

    int s[EPT], d[EPT];
    int cbase = blockIdx.x * CHUNK;
#pragma unroll
    for (int k = 0; k < EPT; k++) {
        int idx = cbase + k * 256 + t;
        if (idx < E) {
            s[k] = src[idx];
            d[k] = dst[idx];
            atomicAdd(&cnt[d[k] >> BKT_SHIFT], 1);
        } else {
            d[k] = -1;
        }
    }
    __syncthreads();
    for (int b = t; b < NB; b += 256) {
        int c = cnt[b];
        if (c) base[b] = atomicAdd(&cursorB[b], c);
    }
    __syncthreads();
#pragma unroll
    for (int k = 0; k < EPT; k++) {
        if (d[k] >= 0) {
            int b = d[k] >> BKT_SHIFT;
            int pos = base[b] + atomicAdd(&cnt2[b], 1);
            pairs[pos] = (s[k] << BKT_SHIFT) | (d[k] & (NBK - 1));
        }
    }
}

// ---------------------------------------------------------- dense transform
template <int K>
__global__ __launch_bounds__(256) void k_transform(
    const float* __restrict__ h, const float* __restrict__ W,
    const float* __restrict__ a_s, const float* __restrict__ a_d,
    float* __restrict__ hs, float* __restrict__ asrc, float* __restrict__ adst, int N) {
    __shared__ float Ws[K * 32];
    __shared__ float as_s[32], ad_s[32];
    int t = threadIdx.x;
    for (int i = t; i < K * 32; i += 256) Ws[i] = W[i];
    if (t < 32) { as_s[t] = a_s[t]; ad_s[t] = a_d[t]; }
    __syncthreads();

    int n = blockIdx.x * 8 + (t >> 5);
    int d = t & 31;
    if (n >= N) return;

    float hval = (d < K) ? h[n * K + d] : 0.f;
    float acc = 0.f;
#pragma unroll
    for (int k = 0; k < K; k++) {
        float hk = __shfl(hval, k, 32);
        acc += hk * Ws[k * 32 + d];
    }
    hs[n * 32 + d] = acc;

    float r1 = acc * as_s[d];
    float r2 = acc * ad_s[d];
#pragma unroll
    for (int off = 16; off > 0; off >>= 1) {
        r1 += __shfl_xor(r1, off, 32);
        r2 += __shfl_xor(r2, off, 32);
    }
    if (d == 0) { asrc[n] = r1; adst[n] = r2; }
}

// ---------------------------------------------------------- bucketed gather
// One edge per lane. The 9 loads (asrc + 8 x dwordx4 of the 128-B hs row)
// are emitted via inline asm in pinned program order -> 9 in flight per
// lane; one vmcnt(0) drain; sched_barrier blocks hoisting (rule #18).
// Single base address + offset: immediates keeps VGPR ~48.
__global__ __launch_bounds__(256, 6) void k_gather(
    const float* __restrict__ hs, const float* __restrict__ asrc,
    const float* __restrict__ adst, const int* __restrict__ offs,
    const int* __restrict__ pairs, const float* __restrict__ bias,
    float* __restrict__ out) {
    __shared__ float acc[NBK * ACCW];
    __shared__ float den[NBK];
    __shared__ float adst_s[NBK];
    int t = threadIdx.x;
    int node0 = blockIdx.x << BKT_SHIFT;
    for (int i = t; i < NBK * ACCW; i += 256) acc[i] = 0.f;
    if (t < NBK) {
        den[t] = 0.f;
        adst_s[t] = adst[node0 + t];
    }
    __syncthreads();

    int beg = offs[blockIdx.x], end = offs[blockIdx.x + 1];

#define ACC4(J, R)                                  \
    atomicAdd(ap + 4 * J + 0, ex * R.x);            \
    atomicAdd(ap + 4 * J + 1, ex * R.y);            \
    atomicAdd(ap + 4 * J + 2, ex * R.z);            \
    atomicAdd(ap + 4 * J + 3, ex * R.w)

    for (int e = beg + t; e < end; e += 256) {
        int pk = pairs[e];
        int s = pk >> BKT_SHIFT;
        int dl = pk & (NBK - 1);
        const float* rowp = hs + ((size_t)s << 5);
        const float* asp = asrc + s;
        float asv;
        float4 r0, r1, r2, r3, r4, r5, r6, r7;
        asm volatile("global_load_dword %0, %1, off"
                     : "=&v"(asv) : "v"(asp) : "memory");
        asm volatile("global_load_dwordx4 %0, %1, off"
                     : "=&v"(r0) : "v"(rowp) : "memory");
        asm volatile("global_load_dwordx4 %0, %1, off offset:16"
                     : "=&v"(r1) : "v"(rowp) : "memory");
        asm volatile("global_load_dwordx4 %0, %1, off offset:32"
                     : "=&v"(r2) : "v"(rowp) : "memory");
        asm volatile("global_load_dwordx4 %0, %1, off offset:48"
                     : "=&v"(r3) : "v"(rowp) : "memory");
        asm volatile("global_load_dwordx4 %0, %1, off offset:64"
                     : "=&v"(r4) : "v"(rowp) : "memory");
        asm volatile("global_load_dwordx4 %0, %1, off offset:80"
                     : "=&v"(r5) : "v"(rowp) : "memory");
        asm volatile("global_load_dwordx4 %0, %1, off offset:96"
                     : "=&v"(r6) : "v"(rowp) : "memory");
        asm volatile("global_load_dwordx4 %0, %1, off offset:112"
                     : "=&v"(r7) : "v"(rowp) : "memory");
        asm volatile("s_waitcnt vmcnt(0)" ::: "memory");
        __builtin_amdgcn_sched_barrier(0);

        float ex = __expf(lrelu(asv + adst_s[dl]));
        float* ap = &acc[dl * ACCW];
        atomicAdd(&den[dl], ex);
        ACC4(0, r0); ACC4(1, r1); ACC4(2, r2); ACC4(3, r3);
        ACC4(4, r4); ACC4(5, r5); ACC4(6, r6); ACC4(7, r7);
    }
#undef ACC4
    __syncthreads();

    int d = t & 31;
    int g = t >> 5;
    float bd = bias[d];
    for (int ln = g; ln < NBK; ln += 8) {
        int n = node0 + ln;
        float exs = __expf(lrelu(asrc[n] + adst_s[ln]));  // self loop
        float v = hs[n * 32 + d];
        float num = acc[ln * ACCW + d] + exs * v;
        float dn = den[ln] + exs;
        out[n * 32 + d] = fmaxf(num / dn + bd, 0.f);
    }
}

// ---------------------------------------------------------------- launcher
extern "C" void kernel_launch(void* const* d_in, const int* in_sizes, int n_in,
                              void* d_out, int out_size, void* d_ws, size_t ws_size,
                              hipStream_t stream) {
    const float* x      = (const float*)d_in[0];
    const int*   ei     = (const int*)d_in[1];
    const float* W0     = (const float*)d_in[2];
    const float* a_src0 = (const float*)d_in[3];
    const float* a_dst0 = (const float*)d_in[4];
    const float* b0     = (const float*)d_in[5];
    const float* W      = (const float*)d_in[6];
    const float* a_src  = (const float*)d_in[7];
    const float* a_dst  = (const float*)d_in[8];
    const float* b      = (const float*)d_in[9];

    const int F = 3;
    const int N = in_sizes[0] / F;   // 320000
    const int E = in_sizes[1] / 2;   // 5120000
    const int* src = ei;
    const int* dst = ei + E;

    // workspace carve
    int*   pairs   = (int*)d_ws;                         // E (packed src|dl)
    float* HS      = (float*)(pairs + E);                // N*32
    float* asrcv   = HS + (size_t)N * 32;                // N
    float* adstv   = asrcv + N;                          // N
    int*   counts  = (int*)(adstv + N);                  // NB
    int*   offs    = counts + NB;                        // NB+1
    int*   cursorB = offs + NB + 1;                      // NB
    float* outp    = (float*)d_out;

    const int T = 256;
    int nchunks = (E + CHUNK - 1) / CHUNK;  // 1250

    // ---- bucket partition build (once; shared by all 3 layers) ----
    hipMemsetAsync(counts, 0, NB * sizeof(int), stream);
    k_hist<<<nchunks, T, 0, stream>>>(dst, E, counts);
    k_scan<<<1, T, 0, stream>>>(counts, offs, cursorB, E);
    k_partition<<<nchunks, T, 0, stream>>>(src, dst, E, cursorB, pairs);

    dim3 gridT(N / 8);   // 8 nodes / block
    dim3 gridG(NB);      // 1 bucket / block

    // ---- layer 0: x(N,3) -> d_out ----
    k_transform<3><<<gridT, T, 0, stream>>>(x, W0, a_src0, a_dst0, HS, asrcv, adstv, N);
    k_gather<<<gridG, T, 0, stream>>>(HS, asrcv, adstv, offs, pairs, b0, outp);

    // ---- layer 1: d_out -> d_out ----
    k_transform<32><<<gridT, T, 0, stream>>>(outp, W, a_src, a_dst, HS, asrcv, adstv, N);
    k_gather<<<gridG, T, 0, stream>>>(HS, asrcv, adstv, offs, pairs, b, outp);

    // ---- layer 2: d_out -> d_out ----
    k_transform<32><<<gridT, T, 0, stream>>>(outp, W + 1024, a_src + 32, a_dst + 32,
                                             HS, asrcv, adstv, N);
    k_gather<<<gridG, T, 0, stream>>>(HS, asrcv, adstv, offs, pairs, b + 32, outp);
}